// Round 17
// baseline (253.819 us; speedup 1.0000x reference)
//
#include <hip/hip_runtime.h>
#include <hip/hip_bf16.h>

// B=4, S=2048, D=1024, H=16, HD=64
constexpr int Sc = 2048, Dc = 1024;

typedef __attribute__((ext_vector_type(8))) short bf16x8;
typedef __attribute__((ext_vector_type(4))) short short4v;
typedef __attribute__((ext_vector_type(4))) float f32x4;
typedef __attribute__((ext_vector_type(16))) float f32x16;

static __device__ __forceinline__ short f2bf(float f) {
  __hip_bfloat16 h = __float2bfloat16(f);
  short s; __builtin_memcpy(&s, &h, 2);
  return s;
}

// packed f32x2 -> bf16x2 (RNE), single instruction on gfx950 (HW-verified r6)
static __device__ __forceinline__ unsigned int cvtpk(float lo, float hi) {
  unsigned int r;
  asm("v_cvt_pk_bf16_f32 %0, %1, %2" : "=v"(r) : "v"(lo), "v"(hi));
  return r;
}

typedef __attribute__((address_space(3))) short lds_short_t;

// async global->LDS, 16B per lane; LDS dest = wave-uniform base + lane*16
static __device__ __forceinline__ void gload16(const short* g, lds_short_t* l) {
  __builtin_amdgcn_global_load_lds(
      (const __attribute__((address_space(1))) unsigned int*)g,
      (__attribute__((address_space(3))) unsigned int*)l, 16, 0, 0);
}

__global__ __launch_bounds__(256) void cvt_f32_bf16(const float* __restrict__ src,
                                                    short* __restrict__ dst,
                                                    int n4) {
  int i = blockIdx.x * 256 + threadIdx.x;
  if (i >= n4) return;
  float4 v = ((const float4*)src)[i];
  short4v o;
  o.x = f2bf(v.x); o.y = f2bf(v.y); o.z = f2bf(v.z); o.w = f2bf(v.w);
  ((short4v*)dst)[i] = o;
}

// all 4 weight matrices in one launch: gridDim=(1024,4)
__global__ __launch_bounds__(256) void cvt_w4(const float* __restrict__ w0,
                                              const float* __restrict__ w1,
                                              const float* __restrict__ w2,
                                              const float* __restrict__ w3,
                                              short* __restrict__ dst) {
  const int y = blockIdx.y;
  const float* src = (y == 0) ? w0 : (y == 1) ? w1 : (y == 2) ? w2 : w3;
  int i = blockIdx.x * 256 + threadIdx.x;  // < 262144 exactly
  float4 v = ((const float4*)src)[i];
  short4v o;
  o.x = f2bf(v.x); o.y = f2bf(v.y); o.z = f2bf(v.z); o.w = f2bf(v.w);
  ((short4v*)(dst))[(size_t)y * 262144 + i] = o;
}

// ---------------------------------------------------------------------------
// 128x128 GEMM, BK=64, single-barrier double-buffer (r11, proven).
// MODE 0: QKV fused epilogue -> Qb (prescaled), Kb, Vt.  MODE 1: f32 + bias.
// ---------------------------------------------------------------------------
template <int MODE>
__global__ __launch_bounds__(256) void gemm_db(
    const short* __restrict__ A, const short* __restrict__ W,
    const float* __restrict__ bias, short* __restrict__ Qb,
    short* __restrict__ Kb, short* __restrict__ Vt, float* __restrict__ outF) {
  __shared__ short As[2][128 * 64];
  __shared__ short Bs[2][128 * 64];
  const int tid = threadIdx.x;
  const int m0 = blockIdx.x * 128, n0 = blockIdx.y * 128;
  const int lane = tid & 63, w = tid >> 6;
  const int wr = w >> 1, wc = w & 1;
  const int ll = lane & 15, lh = lane >> 4;

  lds_short_t* As3 = (lds_short_t*)&As[0][0];
  lds_short_t* Bs3 = (lds_short_t*)&Bs[0][0];

  const short* Abase[4];
  const short* Wbase[4];
  int dstOff[4];
#pragma unroll
  for (int i = 0; i < 4; ++i) {
    int slot = i * 256 + tid;
    int row = slot >> 3;
    int gp = (slot & 7) ^ (row & 7);
    Abase[i] = A + (size_t)(m0 + row) * 1024 + gp * 8;
    Wbase[i] = W + (size_t)(n0 + row) * 1024 + gp * 8;
    dstOff[i] = (i * 256 + w * 64) * 8;
  }

  f32x4 acc[4][4] = {};

  // prologue: stage K-tile 0 into buf 0
#pragma unroll
  for (int i = 0; i < 4; ++i) gload16(Abase[i], As3 + dstOff[i]);
#pragma unroll
  for (int i = 0; i < 4; ++i) gload16(Wbase[i], Bs3 + dstOff[i]);
  int cur = 0;

  for (int k0 = 0; k0 < 1024; k0 += 64) {
    __syncthreads();  // buf[cur] staged for all waves; buf^1 free to refill
    if (k0 < 960) {
      int nb = (cur ^ 1) * 8192;
#pragma unroll
      for (int i = 0; i < 4; ++i) gload16(Abase[i] + k0 + 64, As3 + nb + dstOff[i]);
#pragma unroll
      for (int i = 0; i < 4; ++i) gload16(Wbase[i] + k0 + 64, Bs3 + nb + dstOff[i]);
    }

    bf16x8 fa[4][2], fb[4][2];
#pragma unroll
    for (int mi = 0; mi < 4; ++mi) {
      int r = wr * 64 + mi * 16 + ll;
#pragma unroll
      for (int kh = 0; kh < 2; ++kh)
        fa[mi][kh] =
            *(const bf16x8*)&As[cur][r * 64 + (((kh * 4 + lh) ^ (ll & 7)) * 8)];
    }
#pragma unroll
    for (int ni = 0; ni < 4; ++ni) {
      int r = wc * 64 + ni * 16 + ll;
#pragma unroll
      for (int kh = 0; kh < 2; ++kh)
        fb[ni][kh] =
            *(const bf16x8*)&Bs[cur][r * 64 + (((kh * 4 + lh) ^ (ll & 7)) * 8)];
    }
    __builtin_amdgcn_s_setprio(1);
#pragma unroll
    for (int mi = 0; mi < 4; ++mi)
#pragma unroll
      for (int ni = 0; ni < 4; ++ni)
#pragma unroll
        for (int kh = 0; kh < 2; ++kh)
          acc[mi][ni] = __builtin_amdgcn_mfma_f32_16x16x32_bf16(
              fa[mi][kh], fb[ni][kh], acc[mi][ni], 0, 0, 0);
    __builtin_amdgcn_s_setprio(0);
    cur ^= 1;
  }

#pragma unroll
  for (int mi = 0; mi < 4; ++mi) {
#pragma unroll
    for (int ni = 0; ni < 4; ++ni) {
#pragma unroll
      for (int r = 0; r < 4; ++r) {
        int row = m0 + wr * 64 + mi * 16 + lh * 4 + r;
        int n = n0 + wc * 64 + ni * 16 + ll;
        float v = acc[mi][ni][r];
        if constexpr (MODE == 1) {
          outF[(size_t)row * 1024 + n] = v + bias[n];
        } else {
          if (n < 1024) {
            Qb[(size_t)row * 1024 + n] = f2bf(v * 0.18033688f);  // scale*log2e
          } else if (n < 2048) {
            Kb[(size_t)row * 1024 + (n - 1024)] = f2bf(v);
          } else {
            int cc = n - 2048, hh = cc >> 6, dd = cc & 63;
            int bb = row >> 11, ss = row & 2047;
            Vt[(size_t)((bb * 16 + hh) * 64 + dd) * 2048 + ss] = f2bf(v);
          }
        }
      }
    }
  }
}

// ---------------------------------------------------------------------------
// attn v12 = r13's proven v9 per-tile blocks, software-pipelined 1 tile deep
// within each wave (T15 pattern): iteration kb issues QK(kb) MFMAs FIRST,
// then finish(kb-1) = softmax+pack+PV — softmax VALU overlaps QK's MFMA-pipe
// time, and PV queues behind QK keeping the MFMA pipe full. Triple-buffered
// LDS (48KB): finish(kb-1) reads V from buf[(kb-1)%3] while prefetch fills
// buf[(kb+1)%3] (distinct mod 3); top barrier recycles the 3rd buffer and
// drains DMA (same proven single-barrier discipline). Scores in two
// statically-named register pairs (svP/svN, explicit copy — rule #20 safe).
// Grid 1024, PERM balancing (proven r13 config).
// ---------------------------------------------------------------------------
__global__ __launch_bounds__(256, 3) void attn_v12(const short* __restrict__ Q,
                                                   const short* __restrict__ K,
                                                   const short* __restrict__ Vt,
                                                   short* __restrict__ AO) {
  __shared__ short Ks[3][64 * 64];
  __shared__ short Vs[3][64 * 64];
  const int tid = threadIdx.x, lane = tid & 63, w = tid >> 6;
  const int l31 = lane & 31, lh2 = lane >> 5;
  const int id = blockIdx.x;
  const int bh = id & 63;
  const int qs = id >> 6;
  const int jj = qs >> 2;
  const int qb = (jj == 0) ? qs : (jj == 1) ? 19 - qs : (jj == 2) ? qs - 4 : 23 - qs;
  const int b = bh >> 4, h = bh & 15;
  const int q0 = qb * 128;
  const int R = q0 + w * 32;             // wave's first q-row
  const int kw_last = (R + 31) >> 6;     // wave's diagonal k-tile
  const int kb_max = (q0 + 127) >> 6;    // block's last k-tile
  const short* Qp = Q + (size_t)b * Sc * Dc + h * 64;
  const short* Kp = K + (size_t)b * Sc * Dc + h * 64;
  const short* Vp = Vt + (size_t)bh * 64 * Sc;

  lds_short_t* Ks3 = (lds_short_t*)Ks;
  lds_short_t* Vs3 = (lds_short_t*)Vs;

  bf16x8 qf[4];
#pragma unroll
  for (int dk = 0; dk < 4; ++dk)
    qf[dk] = *(const bf16x8*)&Qp[(size_t)(R + l31) * Dc + dk * 16 + lh2 * 8];

  const short* Kst[2];
  const short* Vst[2];
  int ldsOff[2];
#pragma unroll
  for (int i = 0; i < 2; ++i) {
    int slot = i * 256 + w * 64 + lane;
    int row = slot >> 3;
    int col = ((slot & 7) ^ (row & 7)) * 8;  // pre-swizzled source group
    Kst[i] = Kp + (size_t)row * 1024 + col;
    Vst[i] = Vp + (size_t)row * 2048 + col;
    ldsOff[i] = (i * 256 + w * 64) * 8;
  }

  f32x16 o0 = {}, o1 = {};
  float lrun = 0.f;
  f32x16 svPA = {}, svPB = {}, svNA = {}, svNB = {};

  // QK(j) from Ks[ck] -> s0/s1 (verbatim v9 compute, renamed operands)
  auto qkTile = [&](int j, int ck, f32x16& s0, f32x16& s1) {
    const bool skipHi = (j == kw_last) && ((R & 63) == 0);
#pragma unroll
    for (int r = 0; r < 16; ++r) { s0[r] = 0.f; s1[r] = 0.f; }
    {
      const int row = l31, rx = row & 7;
#pragma unroll
      for (int dk = 0; dk < 4; ++dk) {
        bf16x8 kf =
            *(const bf16x8*)&Ks[ck][row * 64 + (((dk * 2 + lh2) ^ rx) * 8)];
        s0 = __builtin_amdgcn_mfma_f32_32x32x16_bf16(kf, qf[dk], s0, 0, 0, 0);
      }
    }
    if (!skipHi) {
      const int row = 32 + l31, rx = row & 7;
#pragma unroll
      for (int dk = 0; dk < 4; ++dk) {
        bf16x8 kf =
            *(const bf16x8*)&Ks[ck][row * 64 + (((dk * 2 + lh2) ^ rx) * 8)];
        s1 = __builtin_amdgcn_mfma_f32_32x32x16_bf16(kf, qf[dk], s1, 0, 0, 0);
      }
    }
  };

  // finish(j): softmax + pack + PV from Vs[cv] (verbatim v9 blocks)
  auto finishTile = [&](int j, int cv, f32x16& s0, f32x16& s1) {
    const bool diag = (j == kw_last);
    const bool skipHi = diag && ((R & 63) == 0);

    float ts = 0.f;
    if (!diag) {
#pragma unroll
      for (int r = 0; r < 16; ++r) {
        float e0 = exp2f(s0[r]);
        float e1 = exp2f(s1[r]);
        s0[r] = e0; s1[r] = e1;
        ts += e0 + e1;
      }
    } else if (skipHi) {
#pragma unroll
      for (int r = 0; r < 16; ++r) {
        int kl = (r & 3) + 8 * (r >> 2) + 4 * lh2;
        float e = (kl > l31) ? 0.f : exp2f(s0[r]);
        s0[r] = e;
        ts += e;
      }
    } else {
#pragma unroll
      for (int r = 0; r < 16; ++r) {
        float e = exp2f(s0[r]);
        s0[r] = e;
        ts += e;
      }
#pragma unroll
      for (int r = 0; r < 16; ++r) {
        int kl = (r & 3) + 8 * (r >> 2) + 4 * lh2;
        float e = (kl > l31) ? 0.f : exp2f(s1[r]);
        s1[r] = e;
        ts += e;
      }
    }
    lrun += ts;

    short4v pa[8];
#pragma unroll
    for (int t = 0; t < 4; ++t) {
      union { unsigned int u[2]; short4v s4; } pk;
      pk.u[0] = cvtpk(s0[4 * t + 0], s0[4 * t + 1]);
      pk.u[1] = cvtpk(s0[4 * t + 2], s0[4 * t + 3]);
      pa[t] = pk.s4;
    }
    if (skipHi) {
      const int r0 = l31, rx0 = r0 & 7;
      const int r1 = 32 + l31, rx1 = r1 & 7;
#pragma unroll
      for (int t = 0; t < 4; ++t) {
        short4v vb0 =
            *(const short4v*)&Vs[cv][r0 * 64 + ((t ^ rx0) * 8) + lh2 * 4];
        o0 = __builtin_amdgcn_mfma_f32_32x32x8bf16_1k(pa[t], vb0, o0, 0, 0, 0);
        short4v vb1 =
            *(const short4v*)&Vs[cv][r1 * 64 + ((t ^ rx1) * 8) + lh2 * 4];
        o1 = __builtin_amdgcn_mfma_f32_32x32x8bf16_1k(pa[t], vb1, o1, 0, 0, 0);
      }
    } else {
#pragma unroll
      for (int t = 0; t < 4; ++t) {
        union { unsigned int u[2]; short4v s4; } pk;
        pk.u[0] = cvtpk(s1[4 * t + 0], s1[4 * t + 1]);
        pk.u[1] = cvtpk(s1[4 * t + 2], s1[4 * t + 3]);
        pa[4 + t] = pk.s4;
      }
      const int r0 = l31, rx0 = r0 & 7;
      const int r1 = 32 + l31, rx1 = r1 & 7;
#pragma unroll
      for (int t = 0; t < 8; ++t) {
        short4v vb0 =
            *(const short4v*)&Vs[cv][r0 * 64 + ((t ^ rx0) * 8) + lh2 * 4];
        o0 = __builtin_amdgcn_mfma_f32_32x32x8bf16_1k(pa[t], vb0, o0, 0, 0, 0);
      }
#pragma unroll
      for (int t = 0; t < 8; ++t) {
        short4v vb1 =
            *(const short4v*)&Vs[cv][r1 * 64 + ((t ^ rx1) * 8) + lh2 * 4];
        o1 = __builtin_amdgcn_mfma_f32_32x32x8bf16_1k(pa[t], vb1, o1, 0, 0, 0);
      }
    }
  };

  // prologue: stage tile 0 into buf 0
#pragma unroll
  for (int i = 0; i < 2; ++i) {
    gload16(Kst[i], Ks3 + ldsOff[i]);
    gload16(Vst[i], Vs3 + ldsOff[i]);
  }
  int cc = 0, cn = 1, cp = 2;  // current / next(prefetch) / prev(V for finish)

  for (int kb = 0; kb <= kb_max; ++kb) {
    // barrier: tile kb DMA complete (vmcnt drained) AND all waves done with
    // iteration kb-1's reads (K from old cc, V from old cp) -> buf[cn],
    // which held V(kb-2), is safe to overwrite.
    __syncthreads();
    if (kb < kb_max) {
#pragma unroll
      for (int i = 0; i < 2; ++i) {
        gload16(Kst[i] + (size_t)(kb + 1) * 65536, Ks3 + cn * 4096 + ldsOff[i]);
        gload16(Vst[i] + (kb + 1) * 64, Vs3 + cn * 4096 + ldsOff[i]);
      }
    }

    if (kb <= kw_last) qkTile(kb, cc, svNA, svNB);
    if (kb >= 1 && (kb - 1) <= kw_last) finishTile(kb - 1, cp, svPA, svPB);
    if (kb <= kw_last) { svPA = svNA; svPB = svNB; }

    int t = cp; cp = cc; cc = cn; cn = t;
  }
  // tail: waves whose diagonal tile is the block's last tile
  if (kw_last == kb_max) finishTile(kb_max, kb_max % 3, svPA, svPB);

  // epilogue: denominator = own + partner(lane^32), redistribute per q-row
  float ltot = lrun + __shfl_xor(lrun, 32);
#pragma unroll
  for (int r = 0; r < 16; ++r) {
    int qr = (r & 3) + 8 * (r >> 2) + 4 * lh2;
    float lq = __shfl(ltot, qr);
    float inv = 1.0f / lq;
    int rowg = R + qr;
    AO[((size_t)(b * Sc + rowg)) * Dc + h * 64 + l31] = f2bf(o0[r] * inv);
    AO[((size_t)(b * Sc + rowg)) * Dc + h * 64 + 32 + l31] = f2bf(o1[r] * inv);
  }
}

extern "C" void kernel_launch(void* const* d_in, const int* in_sizes, int n_in,
                              void* d_out, int out_size, void* d_ws,
                              size_t ws_size, hipStream_t stream) {
  const float* x = (const float*)d_in[0];
  const float* Wq = (const float*)d_in[1];
  const float* Wk = (const float*)d_in[2];
  const float* Wv = (const float*)d_in[3];
  const float* Wo = (const float*)d_in[4];
  const float* bo = (const float*)d_in[5];
  float* out = (float*)d_out;

  short* Qb = (short*)d_out;
  short* Kb = Qb + (size_t)8192 * 1024;
  short* xb = (short*)d_ws;
  short* AOb = xb;  // xb dead after QKV GEMM; attention writes AOb
  short* Wc = xb + (size_t)8192 * 1024;
  short* Vt = Wc + (size_t)4096 * 1024;

  dim3 blk(256);
  hipLaunchKernelGGL(cvt_f32_bf16, dim3(8192), blk, 0, stream, x, xb, 2097152);
  hipLaunchKernelGGL(cvt_w4, dim3(1024, 4), blk, 0, stream, Wq, Wk, Wv, Wo, Wc);

  hipLaunchKernelGGL((gemm_db<0>), dim3(64, 24), blk, 0, stream, xb, Wc,
                     (const float*)nullptr, Qb, Kb, Vt, (float*)nullptr);

  hipLaunchKernelGGL(attn_v12, dim3(1024), blk, 0, stream, Qb, Kb, Vt, AOb);

  hipLaunchKernelGGL((gemm_db<1>), dim3(64, 8), blk, 0, stream, AOb,
                     Wc + (size_t)3072 * 1024, bo, (short*)nullptr,
                     (short*)nullptr, (short*)nullptr, out);
}

// Round 18
// 212.835 us; speedup vs baseline: 1.1926x; 1.1926x over previous
//
#include <hip/hip_runtime.h>
#include <hip/hip_bf16.h>

// B=4, S=2048, D=1024, H=16, HD=64
constexpr int Sc = 2048, Dc = 1024;

typedef __attribute__((ext_vector_type(8))) short bf16x8;
typedef __attribute__((ext_vector_type(4))) short short4v;
typedef __attribute__((ext_vector_type(4))) float f32x4;
typedef __attribute__((ext_vector_type(16))) float f32x16;

static __device__ __forceinline__ short f2bf(float f) {
  __hip_bfloat16 h = __float2bfloat16(f);
  short s; __builtin_memcpy(&s, &h, 2);
  return s;
}

// packed f32x2 -> bf16x2 (RNE), single instruction on gfx950 (HW-verified r6)
static __device__ __forceinline__ unsigned int cvtpk(float lo, float hi) {
  unsigned int r;
  asm("v_cvt_pk_bf16_f32 %0, %1, %2" : "=v"(r) : "v"(lo), "v"(hi));
  return r;
}

typedef __attribute__((address_space(3))) short lds_short_t;

// async global->LDS, 16B per lane; LDS dest = wave-uniform base + lane*16
static __device__ __forceinline__ void gload16(const short* g, lds_short_t* l) {
  __builtin_amdgcn_global_load_lds(
      (const __attribute__((address_space(1))) unsigned int*)g,
      (__attribute__((address_space(3))) unsigned int*)l, 16, 0, 0);
}

__global__ __launch_bounds__(256) void cvt_f32_bf16(const float* __restrict__ src,
                                                    short* __restrict__ dst,
                                                    int n4) {
  int i = blockIdx.x * 256 + threadIdx.x;
  if (i >= n4) return;
  float4 v = ((const float4*)src)[i];
  short4v o;
  o.x = f2bf(v.x); o.y = f2bf(v.y); o.z = f2bf(v.z); o.w = f2bf(v.w);
  ((short4v*)dst)[i] = o;
}

// all 4 weight matrices in one launch: gridDim=(1024,4)
__global__ __launch_bounds__(256) void cvt_w4(const float* __restrict__ w0,
                                              const float* __restrict__ w1,
                                              const float* __restrict__ w2,
                                              const float* __restrict__ w3,
                                              short* __restrict__ dst) {
  const int y = blockIdx.y;
  const float* src = (y == 0) ? w0 : (y == 1) ? w1 : (y == 2) ? w2 : w3;
  int i = blockIdx.x * 256 + threadIdx.x;  // < 262144 exactly
  float4 v = ((const float4*)src)[i];
  short4v o;
  o.x = f2bf(v.x); o.y = f2bf(v.y); o.z = f2bf(v.z); o.w = f2bf(v.w);
  ((short4v*)(dst))[(size_t)y * 262144 + i] = o;
}

// ---------------------------------------------------------------------------
// 128x128 GEMM, BK=64, single-barrier double-buffer (r11, proven).
// r18: 1-D grid + XCD-chunked swizzle (T1) — each XCD gets a contiguous
// chunk of tiles sharing W-panels in its private L2. Pure bijective index
// remap (nwg % 8 == 0 for both launches), zero correctness risk.
// MODE 0: QKV fused epilogue -> Qb (prescaled), Kb, Vt.  MODE 1: f32 + bias.
// ---------------------------------------------------------------------------
template <int MODE>
__global__ __launch_bounds__(256) void gemm_db(
    const short* __restrict__ A, const short* __restrict__ W,
    const float* __restrict__ bias, short* __restrict__ Qb,
    short* __restrict__ Kb, short* __restrict__ Vt, float* __restrict__ outF) {
  __shared__ short As[2][128 * 64];
  __shared__ short Bs[2][128 * 64];
  const int tid = threadIdx.x;
  // XCD-chunked swizzle: id%8 = XCD -> chunk of nwg/8 consecutive tiles
  const int nwg = gridDim.x;
  const int id = blockIdx.x;
  const int swz = (id & 7) * (nwg >> 3) + (id >> 3);
  const int m0 = (swz & 63) * 128, n0 = (swz >> 6) * 128;
  const int lane = tid & 63, w = tid >> 6;
  const int wr = w >> 1, wc = w & 1;
  const int ll = lane & 15, lh = lane >> 4;

  lds_short_t* As3 = (lds_short_t*)&As[0][0];
  lds_short_t* Bs3 = (lds_short_t*)&Bs[0][0];

  const short* Abase[4];
  const short* Wbase[4];
  int dstOff[4];
#pragma unroll
  for (int i = 0; i < 4; ++i) {
    int slot = i * 256 + tid;
    int row = slot >> 3;
    int gp = (slot & 7) ^ (row & 7);
    Abase[i] = A + (size_t)(m0 + row) * 1024 + gp * 8;
    Wbase[i] = W + (size_t)(n0 + row) * 1024 + gp * 8;
    dstOff[i] = (i * 256 + w * 64) * 8;
  }

  f32x4 acc[4][4] = {};

  // prologue: stage K-tile 0 into buf 0
#pragma unroll
  for (int i = 0; i < 4; ++i) gload16(Abase[i], As3 + dstOff[i]);
#pragma unroll
  for (int i = 0; i < 4; ++i) gload16(Wbase[i], Bs3 + dstOff[i]);
  int cur = 0;

  for (int k0 = 0; k0 < 1024; k0 += 64) {
    __syncthreads();  // buf[cur] staged for all waves; buf^1 free to refill
    if (k0 < 960) {
      int nb = (cur ^ 1) * 8192;
#pragma unroll
      for (int i = 0; i < 4; ++i) gload16(Abase[i] + k0 + 64, As3 + nb + dstOff[i]);
#pragma unroll
      for (int i = 0; i < 4; ++i) gload16(Wbase[i] + k0 + 64, Bs3 + nb + dstOff[i]);
    }

    bf16x8 fa[4][2], fb[4][2];
#pragma unroll
    for (int mi = 0; mi < 4; ++mi) {
      int r = wr * 64 + mi * 16 + ll;
#pragma unroll
      for (int kh = 0; kh < 2; ++kh)
        fa[mi][kh] =
            *(const bf16x8*)&As[cur][r * 64 + (((kh * 4 + lh) ^ (ll & 7)) * 8)];
    }
#pragma unroll
    for (int ni = 0; ni < 4; ++ni) {
      int r = wc * 64 + ni * 16 + ll;
#pragma unroll
      for (int kh = 0; kh < 2; ++kh)
        fb[ni][kh] =
            *(const bf16x8*)&Bs[cur][r * 64 + (((kh * 4 + lh) ^ (ll & 7)) * 8)];
    }
    __builtin_amdgcn_s_setprio(1);
#pragma unroll
    for (int mi = 0; mi < 4; ++mi)
#pragma unroll
      for (int ni = 0; ni < 4; ++ni)
#pragma unroll
        for (int kh = 0; kh < 2; ++kh)
          acc[mi][ni] = __builtin_amdgcn_mfma_f32_16x16x32_bf16(
              fa[mi][kh], fb[ni][kh], acc[mi][ni], 0, 0, 0);
    __builtin_amdgcn_s_setprio(0);
    cur ^= 1;
  }

#pragma unroll
  for (int mi = 0; mi < 4; ++mi) {
#pragma unroll
    for (int ni = 0; ni < 4; ++ni) {
#pragma unroll
      for (int r = 0; r < 4; ++r) {
        int row = m0 + wr * 64 + mi * 16 + lh * 4 + r;
        int n = n0 + wc * 64 + ni * 16 + ll;
        float v = acc[mi][ni][r];
        if constexpr (MODE == 1) {
          outF[(size_t)row * 1024 + n] = v + bias[n];
        } else {
          if (n < 1024) {
            Qb[(size_t)row * 1024 + n] = f2bf(v * 0.18033688f);  // scale*log2e
          } else if (n < 2048) {
            Kb[(size_t)row * 1024 + (n - 1024)] = f2bf(v);
          } else {
            int cc = n - 2048, hh = cc >> 6, dd = cc & 63;
            int bb = row >> 11, ss = row & 2047;
            Vt[(size_t)((bb * 16 + hh) * 64 + dd) * 2048 + ss] = f2bf(v);
          }
        }
      }
    }
  }
}

// Causal flash attention, fixed-max softmax, 32x32 MFMA, swapped QK^T
// (v9: proven 78.3us / absmax 0.0166 @ r13 — byte-identical revert after
// v10/v11/v12 restructures all regressed; v12's spill lesson: 32x32 attn
// pipeline state does not fit the VGPR budget).
__global__ __launch_bounds__(256, 4) void attn_v9(const short* __restrict__ Q,
                                                  const short* __restrict__ K,
                                                  const short* __restrict__ Vt,
                                                  short* __restrict__ AO) {
  __shared__ short Ks[2][64 * 64];
  __shared__ short Vs[2][64 * 64];
  const int tid = threadIdx.x, lane = tid & 63, w = tid >> 6;
  const int l31 = lane & 31, lh2 = lane >> 5;
  const int id = blockIdx.x;
  const int bh = id & 63;
  const int qs = id >> 6;
  const int jj = qs >> 2;
  const int qb = (jj == 0) ? qs : (jj == 1) ? 19 - qs : (jj == 2) ? qs - 4 : 23 - qs;
  const int b = bh >> 4, h = bh & 15;
  const int q0 = qb * 128;
  const int R = q0 + w * 32;             // wave's first q-row
  const int kw_last = (R + 31) >> 6;     // wave's diagonal k-tile
  const int kb_max = (q0 + 127) >> 6;    // block's last k-tile
  const short* Qp = Q + (size_t)b * Sc * Dc + h * 64;
  const short* Kp = K + (size_t)b * Sc * Dc + h * 64;
  const short* Vp = Vt + (size_t)bh * 64 * Sc;

  lds_short_t* Ks3 = (lds_short_t*)Ks;
  lds_short_t* Vs3 = (lds_short_t*)Vs;

  bf16x8 qf[4];
#pragma unroll
  for (int dk = 0; dk < 4; ++dk)
    qf[dk] = *(const bf16x8*)&Qp[(size_t)(R + l31) * Dc + dk * 16 + lh2 * 8];

  const short* Kst[2];
  const short* Vst[2];
  int ldsOff[2];
#pragma unroll
  for (int i = 0; i < 2; ++i) {
    int slot = i * 256 + w * 64 + lane;
    int row = slot >> 3;
    int col = ((slot & 7) ^ (row & 7)) * 8;  // pre-swizzled source group
    Kst[i] = Kp + (size_t)row * 1024 + col;
    Vst[i] = Vp + (size_t)row * 2048 + col;
    ldsOff[i] = (i * 256 + w * 64) * 8;
  }

  f32x16 o0 = {}, o1 = {};
  float lrun = 0.f;

#pragma unroll
  for (int i = 0; i < 2; ++i) {
    gload16(Kst[i], Ks3 + ldsOff[i]);
    gload16(Vst[i], Vs3 + ldsOff[i]);
  }
  int cur = 0;

  for (int kb = 0; kb <= kb_max; ++kb) {
    __syncthreads();
    if (kb < kb_max) {
      int nb = cur ^ 1;
#pragma unroll
      for (int i = 0; i < 2; ++i) {
        gload16(Kst[i] + (size_t)(kb + 1) * 65536, Ks3 + nb * 4096 + ldsOff[i]);
        gload16(Vst[i] + (kb + 1) * 64, Vs3 + nb * 4096 + ldsOff[i]);
      }
    }

    if (kb <= kw_last) {
      const bool diag = (kb == kw_last);
      const bool skipHi = diag && ((R & 63) == 0);

      f32x16 sv0 = {}, sv1 = {};
      {
        const int row = l31, rx = row & 7;
#pragma unroll
        for (int dk = 0; dk < 4; ++dk) {
          bf16x8 kf =
              *(const bf16x8*)&Ks[cur][row * 64 + (((dk * 2 + lh2) ^ rx) * 8)];
          sv0 = __builtin_amdgcn_mfma_f32_32x32x16_bf16(kf, qf[dk], sv0, 0, 0, 0);
        }
      }
      if (!skipHi) {
        const int row = 32 + l31, rx = row & 7;
#pragma unroll
        for (int dk = 0; dk < 4; ++dk) {
          bf16x8 kf =
              *(const bf16x8*)&Ks[cur][row * 64 + (((dk * 2 + lh2) ^ rx) * 8)];
          sv1 = __builtin_amdgcn_mfma_f32_32x32x16_bf16(kf, qf[dk], sv1, 0, 0, 0);
        }
      }

      float ts = 0.f;
      if (!diag) {
#pragma unroll
        for (int r = 0; r < 16; ++r) {
          float e0 = exp2f(sv0[r]);
          float e1 = exp2f(sv1[r]);
          sv0[r] = e0; sv1[r] = e1;
          ts += e0 + e1;
        }
      } else if (skipHi) {
#pragma unroll
        for (int r = 0; r < 16; ++r) {
          int kl = (r & 3) + 8 * (r >> 2) + 4 * lh2;
          float e = (kl > l31) ? 0.f : exp2f(sv0[r]);
          sv0[r] = e;
          ts += e;
        }
      } else {
#pragma unroll
        for (int r = 0; r < 16; ++r) {
          float e = exp2f(sv0[r]);
          sv0[r] = e;
          ts += e;
        }
#pragma unroll
        for (int r = 0; r < 16; ++r) {
          int kl = (r & 3) + 8 * (r >> 2) + 4 * lh2;
          float e = (kl > l31) ? 0.f : exp2f(sv1[r]);
          sv1[r] = e;
          ts += e;
        }
      }
      lrun += ts;

      short4v pa[8];
#pragma unroll
      for (int t = 0; t < 4; ++t) {
        union { unsigned int u[2]; short4v s; } pk;
        pk.u[0] = cvtpk(sv0[4 * t + 0], sv0[4 * t + 1]);
        pk.u[1] = cvtpk(sv0[4 * t + 2], sv0[4 * t + 3]);
        pa[t] = pk.s;
      }
      if (skipHi) {
        const int r0 = l31, rx0 = r0 & 7;
        const int r1 = 32 + l31, rx1 = r1 & 7;
#pragma unroll
        for (int t = 0; t < 4; ++t) {
          short4v vb0 =
              *(const short4v*)&Vs[cur][r0 * 64 + ((t ^ rx0) * 8) + lh2 * 4];
          o0 = __builtin_amdgcn_mfma_f32_32x32x8bf16_1k(pa[t], vb0, o0, 0, 0, 0);
          short4v vb1 =
              *(const short4v*)&Vs[cur][r1 * 64 + ((t ^ rx1) * 8) + lh2 * 4];
          o1 = __builtin_amdgcn_mfma_f32_32x32x8bf16_1k(pa[t], vb1, o1, 0, 0, 0);
        }
      } else {
#pragma unroll
        for (int t = 0; t < 4; ++t) {
          union { unsigned int u[2]; short4v s; } pk;
          pk.u[0] = cvtpk(sv1[4 * t + 0], sv1[4 * t + 1]);
          pk.u[1] = cvtpk(sv1[4 * t + 2], sv1[4 * t + 3]);
          pa[4 + t] = pk.s;
        }
        const int r0 = l31, rx0 = r0 & 7;
        const int r1 = 32 + l31, rx1 = r1 & 7;
#pragma unroll
        for (int t = 0; t < 8; ++t) {
          short4v vb0 =
              *(const short4v*)&Vs[cur][r0 * 64 + ((t ^ rx0) * 8) + lh2 * 4];
          o0 = __builtin_amdgcn_mfma_f32_32x32x8bf16_1k(pa[t], vb0, o0, 0, 0, 0);
        }
#pragma unroll
        for (int t = 0; t < 8; ++t) {
          short4v vb1 =
              *(const short4v*)&Vs[cur][r1 * 64 + ((t ^ rx1) * 8) + lh2 * 4];
          o1 = __builtin_amdgcn_mfma_f32_32x32x8bf16_1k(pa[t], vb1, o1, 0, 0, 0);
        }
      }
    }
    cur ^= 1;
  }

  float ltot = lrun + __shfl_xor(lrun, 32);
#pragma unroll
  for (int r = 0; r < 16; ++r) {
    int qr = (r & 3) + 8 * (r >> 2) + 4 * lh2;
    float lq = __shfl(ltot, qr);
    float inv = 1.0f / lq;
    int rowg = R + qr;
    AO[((size_t)(b * Sc + rowg)) * Dc + h * 64 + l31] = f2bf(o0[r] * inv);
    AO[((size_t)(b * Sc + rowg)) * Dc + h * 64 + 32 + l31] = f2bf(o1[r] * inv);
  }
}

extern "C" void kernel_launch(void* const* d_in, const int* in_sizes, int n_in,
                              void* d_out, int out_size, void* d_ws,
                              size_t ws_size, hipStream_t stream) {
  const float* x = (const float*)d_in[0];
  const float* Wq = (const float*)d_in[1];
  const float* Wk = (const float*)d_in[2];
  const float* Wv = (const float*)d_in[3];
  const float* Wo = (const float*)d_in[4];
  const float* bo = (const float*)d_in[5];
  float* out = (float*)d_out;

  short* Qb = (short*)d_out;
  short* Kb = Qb + (size_t)8192 * 1024;
  short* xb = (short*)d_ws;
  short* AOb = xb;  // xb dead after QKV GEMM; attention writes AOb
  short* Wc = xb + (size_t)8192 * 1024;
  short* Vt = Wc + (size_t)4096 * 1024;

  dim3 blk(256);
  hipLaunchKernelGGL(cvt_f32_bf16, dim3(8192), blk, 0, stream, x, xb, 2097152);
  hipLaunchKernelGGL(cvt_w4, dim3(1024, 4), blk, 0, stream, Wq, Wk, Wv, Wo, Wc);

  hipLaunchKernelGGL((gemm_db<0>), dim3(1536), blk, 0, stream, xb, Wc,
                     (const float*)nullptr, Qb, Kb, Vt, (float*)nullptr);

  hipLaunchKernelGGL(attn_v9, dim3(1024), blk, 0, stream, Qb, Kb, Vt, AOb);

  hipLaunchKernelGGL((gemm_db<1>), dim3(512), blk, 0, stream, AOb,
                     Wc + (size_t)3072 * 1024, bo, (short*)nullptr,
                     (short*)nullptr, (short*)nullptr, out);
}

// Round 19
// 180.778 us; speedup vs baseline: 1.4040x; 1.1773x over previous
//
#include <hip/hip_runtime.h>
#include <hip/hip_bf16.h>

// B=4, S=2048, D=1024, H=16, HD=64
constexpr int Sc = 2048, Dc = 1024;

typedef __attribute__((ext_vector_type(8))) short bf16x8;
typedef __attribute__((ext_vector_type(4))) short short4v;
typedef __attribute__((ext_vector_type(4))) float f32x4;
typedef __attribute__((ext_vector_type(16))) float f32x16;

static __device__ __forceinline__ short f2bf(float f) {
  __hip_bfloat16 h = __float2bfloat16(f);
  short s; __builtin_memcpy(&s, &h, 2);
  return s;
}

// packed f32x2 -> bf16x2 (RNE), single instruction on gfx950 (HW-verified r6)
static __device__ __forceinline__ unsigned int cvtpk(float lo, float hi) {
  unsigned int r;
  asm("v_cvt_pk_bf16_f32 %0, %1, %2" : "=v"(r) : "v"(lo), "v"(hi));
  return r;
}

typedef __attribute__((address_space(3))) short lds_short_t;

// async global->LDS, 16B per lane; LDS dest = wave-uniform base + lane*16
static __device__ __forceinline__ void gload16(const short* g, lds_short_t* l) {
  __builtin_amdgcn_global_load_lds(
      (const __attribute__((address_space(1))) unsigned int*)g,
      (__attribute__((address_space(3))) unsigned int*)l, 16, 0, 0);
}

__global__ __launch_bounds__(256) void cvt_f32_bf16(const float* __restrict__ src,
                                                    short* __restrict__ dst,
                                                    int n4) {
  int i = blockIdx.x * 256 + threadIdx.x;
  if (i >= n4) return;
  float4 v = ((const float4*)src)[i];
  short4v o;
  o.x = f2bf(v.x); o.y = f2bf(v.y); o.z = f2bf(v.z); o.w = f2bf(v.w);
  ((short4v*)dst)[i] = o;
}

// all 4 weight matrices in one launch: gridDim=(1024,4)
__global__ __launch_bounds__(256) void cvt_w4(const float* __restrict__ w0,
                                              const float* __restrict__ w1,
                                              const float* __restrict__ w2,
                                              const float* __restrict__ w3,
                                              short* __restrict__ dst) {
  const int y = blockIdx.y;
  const float* src = (y == 0) ? w0 : (y == 1) ? w1 : (y == 2) ? w2 : w3;
  int i = blockIdx.x * 256 + threadIdx.x;  // < 262144 exactly
  float4 v = ((const float4*)src)[i];
  short4v o;
  o.x = f2bf(v.x); o.y = f2bf(v.y); o.z = f2bf(v.z); o.w = f2bf(v.w);
  ((short4v*)(dst))[(size_t)y * 262144 + i] = o;
}

// ---------------------------------------------------------------------------
// 128x128 GEMM, BK=64, single-barrier double-buffer (r11, proven).
// 2-D grid, natural order (r18's XCD swizzle quadrupled FETCH_SIZE: the
// default consecutive-m/same-n order already keeps W panels hot per XCD).
// MODE 0: QKV fused epilogue -> Qb (prescaled), Kb, Vt.  MODE 1: f32 + bias.
// ---------------------------------------------------------------------------
template <int MODE>
__global__ __launch_bounds__(256) void gemm_db(
    const short* __restrict__ A, const short* __restrict__ W,
    const float* __restrict__ bias, short* __restrict__ Qb,
    short* __restrict__ Kb, short* __restrict__ Vt, float* __restrict__ outF) {
  __shared__ short As[2][128 * 64];
  __shared__ short Bs[2][128 * 64];
  const int tid = threadIdx.x;
  const int m0 = blockIdx.x * 128, n0 = blockIdx.y * 128;
  const int lane = tid & 63, w = tid >> 6;
  const int wr = w >> 1, wc = w & 1;
  const int ll = lane & 15, lh = lane >> 4;

  lds_short_t* As3 = (lds_short_t*)&As[0][0];
  lds_short_t* Bs3 = (lds_short_t*)&Bs[0][0];

  const short* Abase[4];
  const short* Wbase[4];
  int dstOff[4];
#pragma unroll
  for (int i = 0; i < 4; ++i) {
    int slot = i * 256 + tid;
    int row = slot >> 3;
    int gp = (slot & 7) ^ (row & 7);
    Abase[i] = A + (size_t)(m0 + row) * 1024 + gp * 8;
    Wbase[i] = W + (size_t)(n0 + row) * 1024 + gp * 8;
    dstOff[i] = (i * 256 + w * 64) * 8;
  }

  f32x4 acc[4][4] = {};

  // prologue: stage K-tile 0 into buf 0
#pragma unroll
  for (int i = 0; i < 4; ++i) gload16(Abase[i], As3 + dstOff[i]);
#pragma unroll
  for (int i = 0; i < 4; ++i) gload16(Wbase[i], Bs3 + dstOff[i]);
  int cur = 0;

  for (int k0 = 0; k0 < 1024; k0 += 64) {
    __syncthreads();  // buf[cur] staged for all waves; buf^1 free to refill
    if (k0 < 960) {
      int nb = (cur ^ 1) * 8192;
#pragma unroll
      for (int i = 0; i < 4; ++i) gload16(Abase[i] + k0 + 64, As3 + nb + dstOff[i]);
#pragma unroll
      for (int i = 0; i < 4; ++i) gload16(Wbase[i] + k0 + 64, Bs3 + nb + dstOff[i]);
    }

    bf16x8 fa[4][2], fb[4][2];
#pragma unroll
    for (int mi = 0; mi < 4; ++mi) {
      int r = wr * 64 + mi * 16 + ll;
#pragma unroll
      for (int kh = 0; kh < 2; ++kh)
        fa[mi][kh] =
            *(const bf16x8*)&As[cur][r * 64 + (((kh * 4 + lh) ^ (ll & 7)) * 8)];
    }
#pragma unroll
    for (int ni = 0; ni < 4; ++ni) {
      int r = wc * 64 + ni * 16 + ll;
#pragma unroll
      for (int kh = 0; kh < 2; ++kh)
        fb[ni][kh] =
            *(const bf16x8*)&Bs[cur][r * 64 + (((kh * 4 + lh) ^ (ll & 7)) * 8)];
    }
    __builtin_amdgcn_s_setprio(1);
#pragma unroll
    for (int mi = 0; mi < 4; ++mi)
#pragma unroll
      for (int ni = 0; ni < 4; ++ni)
#pragma unroll
        for (int kh = 0; kh < 2; ++kh)
          acc[mi][ni] = __builtin_amdgcn_mfma_f32_16x16x32_bf16(
              fa[mi][kh], fb[ni][kh], acc[mi][ni], 0, 0, 0);
    __builtin_amdgcn_s_setprio(0);
    cur ^= 1;
  }

#pragma unroll
  for (int mi = 0; mi < 4; ++mi) {
#pragma unroll
    for (int ni = 0; ni < 4; ++ni) {
#pragma unroll
      for (int r = 0; r < 4; ++r) {
        int row = m0 + wr * 64 + mi * 16 + lh * 4 + r;
        int n = n0 + wc * 64 + ni * 16 + ll;
        float v = acc[mi][ni][r];
        if constexpr (MODE == 1) {
          outF[(size_t)row * 1024 + n] = v + bias[n];
        } else {
          if (n < 1024) {
            Qb[(size_t)row * 1024 + n] = f2bf(v * 0.18033688f);  // scale*log2e
          } else if (n < 2048) {
            Kb[(size_t)row * 1024 + (n - 1024)] = f2bf(v);
          } else {
            int cc = n - 2048, hh = cc >> 6, dd = cc & 63;
            int bb = row >> 11, ss = row & 2047;
            Vt[(size_t)((bb * 16 + hh) * 64 + dd) * 2048 + ss] = f2bf(v);
          }
        }
      }
    }
  }
}

// Causal flash attention, fixed-max softmax, 32x32 MFMA, swapped QK^T
// (v9: proven 78.3us / absmax 0.0166 @ r13 — best-known attention; all six
// restructures (direct-V, barrier-free, pairing, occupancy cap, in-wave
// pipeline, swizzles) regressed on latency-chain / residency / VGPR walls).
__global__ __launch_bounds__(256, 4) void attn_v9(const short* __restrict__ Q,
                                                  const short* __restrict__ K,
                                                  const short* __restrict__ Vt,
                                                  short* __restrict__ AO) {
  __shared__ short Ks[2][64 * 64];
  __shared__ short Vs[2][64 * 64];
  const int tid = threadIdx.x, lane = tid & 63, w = tid >> 6;
  const int l31 = lane & 31, lh2 = lane >> 5;
  const int id = blockIdx.x;
  const int bh = id & 63;
  const int qs = id >> 6;
  const int jj = qs >> 2;
  const int qb = (jj == 0) ? qs : (jj == 1) ? 19 - qs : (jj == 2) ? qs - 4 : 23 - qs;
  const int b = bh >> 4, h = bh & 15;
  const int q0 = qb * 128;
  const int R = q0 + w * 32;             // wave's first q-row
  const int kw_last = (R + 31) >> 6;     // wave's diagonal k-tile
  const int kb_max = (q0 + 127) >> 6;    // block's last k-tile
  const short* Qp = Q + (size_t)b * Sc * Dc + h * 64;
  const short* Kp = K + (size_t)b * Sc * Dc + h * 64;
  const short* Vp = Vt + (size_t)bh * 64 * Sc;

  lds_short_t* Ks3 = (lds_short_t*)Ks;
  lds_short_t* Vs3 = (lds_short_t*)Vs;

  bf16x8 qf[4];
#pragma unroll
  for (int dk = 0; dk < 4; ++dk)
    qf[dk] = *(const bf16x8*)&Qp[(size_t)(R + l31) * Dc + dk * 16 + lh2 * 8];

  const short* Kst[2];
  const short* Vst[2];
  int ldsOff[2];
#pragma unroll
  for (int i = 0; i < 2; ++i) {
    int slot = i * 256 + w * 64 + lane;
    int row = slot >> 3;
    int col = ((slot & 7) ^ (row & 7)) * 8;  // pre-swizzled source group
    Kst[i] = Kp + (size_t)row * 1024 + col;
    Vst[i] = Vp + (size_t)row * 2048 + col;
    ldsOff[i] = (i * 256 + w * 64) * 8;
  }

  f32x16 o0 = {}, o1 = {};
  float lrun = 0.f;

#pragma unroll
  for (int i = 0; i < 2; ++i) {
    gload16(Kst[i], Ks3 + ldsOff[i]);
    gload16(Vst[i], Vs3 + ldsOff[i]);
  }
  int cur = 0;

  for (int kb = 0; kb <= kb_max; ++kb) {
    __syncthreads();
    if (kb < kb_max) {
      int nb = cur ^ 1;
#pragma unroll
      for (int i = 0; i < 2; ++i) {
        gload16(Kst[i] + (size_t)(kb + 1) * 65536, Ks3 + nb * 4096 + ldsOff[i]);
        gload16(Vst[i] + (kb + 1) * 64, Vs3 + nb * 4096 + ldsOff[i]);
      }
    }

    if (kb <= kw_last) {
      const bool diag = (kb == kw_last);
      const bool skipHi = diag && ((R & 63) == 0);

      f32x16 sv0 = {}, sv1 = {};
      {
        const int row = l31, rx = row & 7;
#pragma unroll
        for (int dk = 0; dk < 4; ++dk) {
          bf16x8 kf =
              *(const bf16x8*)&Ks[cur][row * 64 + (((dk * 2 + lh2) ^ rx) * 8)];
          sv0 = __builtin_amdgcn_mfma_f32_32x32x16_bf16(kf, qf[dk], sv0, 0, 0, 0);
        }
      }
      if (!skipHi) {
        const int row = 32 + l31, rx = row & 7;
#pragma unroll
        for (int dk = 0; dk < 4; ++dk) {
          bf16x8 kf =
              *(const bf16x8*)&Ks[cur][row * 64 + (((dk * 2 + lh2) ^ rx) * 8)];
          sv1 = __builtin_amdgcn_mfma_f32_32x32x16_bf16(kf, qf[dk], sv1, 0, 0, 0);
        }
      }

      float ts = 0.f;
      if (!diag) {
#pragma unroll
        for (int r = 0; r < 16; ++r) {
          float e0 = exp2f(sv0[r]);
          float e1 = exp2f(sv1[r]);
          sv0[r] = e0; sv1[r] = e1;
          ts += e0 + e1;
        }
      } else if (skipHi) {
#pragma unroll
        for (int r = 0; r < 16; ++r) {
          int kl = (r & 3) + 8 * (r >> 2) + 4 * lh2;
          float e = (kl > l31) ? 0.f : exp2f(sv0[r]);
          sv0[r] = e;
          ts += e;
        }
      } else {
#pragma unroll
        for (int r = 0; r < 16; ++r) {
          float e = exp2f(sv0[r]);
          sv0[r] = e;
          ts += e;
        }
#pragma unroll
        for (int r = 0; r < 16; ++r) {
          int kl = (r & 3) + 8 * (r >> 2) + 4 * lh2;
          float e = (kl > l31) ? 0.f : exp2f(sv1[r]);
          sv1[r] = e;
          ts += e;
        }
      }
      lrun += ts;

      short4v pa[8];
#pragma unroll
      for (int t = 0; t < 4; ++t) {
        union { unsigned int u[2]; short4v s; } pk;
        pk.u[0] = cvtpk(sv0[4 * t + 0], sv0[4 * t + 1]);
        pk.u[1] = cvtpk(sv0[4 * t + 2], sv0[4 * t + 3]);
        pa[t] = pk.s;
      }
      if (skipHi) {
        const int r0 = l31, rx0 = r0 & 7;
        const int r1 = 32 + l31, rx1 = r1 & 7;
#pragma unroll
        for (int t = 0; t < 4; ++t) {
          short4v vb0 =
              *(const short4v*)&Vs[cur][r0 * 64 + ((t ^ rx0) * 8) + lh2 * 4];
          o0 = __builtin_amdgcn_mfma_f32_32x32x8bf16_1k(pa[t], vb0, o0, 0, 0, 0);
          short4v vb1 =
              *(const short4v*)&Vs[cur][r1 * 64 + ((t ^ rx1) * 8) + lh2 * 4];
          o1 = __builtin_amdgcn_mfma_f32_32x32x8bf16_1k(pa[t], vb1, o1, 0, 0, 0);
        }
      } else {
#pragma unroll
        for (int t = 0; t < 4; ++t) {
          union { unsigned int u[2]; short4v s; } pk;
          pk.u[0] = cvtpk(sv1[4 * t + 0], sv1[4 * t + 1]);
          pk.u[1] = cvtpk(sv1[4 * t + 2], sv1[4 * t + 3]);
          pa[4 + t] = pk.s;
        }
        const int r0 = l31, rx0 = r0 & 7;
        const int r1 = 32 + l31, rx1 = r1 & 7;
#pragma unroll
        for (int t = 0; t < 8; ++t) {
          short4v vb0 =
              *(const short4v*)&Vs[cur][r0 * 64 + ((t ^ rx0) * 8) + lh2 * 4];
          o0 = __builtin_amdgcn_mfma_f32_32x32x8bf16_1k(pa[t], vb0, o0, 0, 0, 0);
        }
#pragma unroll
        for (int t = 0; t < 8; ++t) {
          short4v vb1 =
              *(const short4v*)&Vs[cur][r1 * 64 + ((t ^ rx1) * 8) + lh2 * 4];
          o1 = __builtin_amdgcn_mfma_f32_32x32x8bf16_1k(pa[t], vb1, o1, 0, 0, 0);
        }
      }
    }
    cur ^= 1;
  }

  float ltot = lrun + __shfl_xor(lrun, 32);
#pragma unroll
  for (int r = 0; r < 16; ++r) {
    int qr = (r & 3) + 8 * (r >> 2) + 4 * lh2;
    float lq = __shfl(ltot, qr);
    float inv = 1.0f / lq;
    int rowg = R + qr;
    AO[((size_t)(b * Sc + rowg)) * Dc + h * 64 + l31] = f2bf(o0[r] * inv);
    AO[((size_t)(b * Sc + rowg)) * Dc + h * 64 + 32 + l31] = f2bf(o1[r] * inv);
  }
}

extern "C" void kernel_launch(void* const* d_in, const int* in_sizes, int n_in,
                              void* d_out, int out_size, void* d_ws,
                              size_t ws_size, hipStream_t stream) {
  const float* x = (const float*)d_in[0];
  const float* Wq = (const float*)d_in[1];
  const float* Wk = (const float*)d_in[2];
  const float* Wv = (const float*)d_in[3];
  const float* Wo = (const float*)d_in[4];
  const float* bo = (const float*)d_in[5];
  float* out = (float*)d_out;

  short* Qb = (short*)d_out;
  short* Kb = Qb + (size_t)8192 * 1024;
  short* xb = (short*)d_ws;
  short* AOb = xb;  // xb dead after QKV GEMM; attention writes AOb
  short* Wc = xb + (size_t)8192 * 1024;
  short* Vt = Wc + (size_t)4096 * 1024;

  dim3 blk(256);
  hipLaunchKernelGGL(cvt_f32_bf16, dim3(8192), blk, 0, stream, x, xb, 2097152);
  hipLaunchKernelGGL(cvt_w4, dim3(1024, 4), blk, 0, stream, Wq, Wk, Wv, Wo, Wc);

  hipLaunchKernelGGL((gemm_db<0>), dim3(64, 24), blk, 0, stream, xb, Wc,
                     (const float*)nullptr, Qb, Kb, Vt, (float*)nullptr);

  hipLaunchKernelGGL(attn_v9, dim3(1024), blk, 0, stream, Qb, Kb, Vt, AOb);

  hipLaunchKernelGGL((gemm_db<1>), dim3(64, 8), blk, 0, stream, AOb,
                     Wc + (size_t)3072 * 1024, bo, (short*)nullptr,
                     (short*)nullptr, (short*)nullptr, out);
}

// Round 20
// 178.552 us; speedup vs baseline: 1.4215x; 1.0125x over previous
//
#include <hip/hip_runtime.h>
#include <hip/hip_bf16.h>

// B=4, S=2048, D=1024, H=16, HD=64
constexpr int Sc = 2048, Dc = 1024;

typedef __attribute__((ext_vector_type(8))) short bf16x8;
typedef __attribute__((ext_vector_type(4))) short short4v;
typedef __attribute__((ext_vector_type(4))) float f32x4;
typedef __attribute__((ext_vector_type(16))) float f32x16;

static __device__ __forceinline__ short f2bf(float f) {
  __hip_bfloat16 h = __float2bfloat16(f);
  short s; __builtin_memcpy(&s, &h, 2);
  return s;
}

// packed f32x2 -> bf16x2 (RNE), single instruction on gfx950 (HW-verified r6)
static __device__ __forceinline__ unsigned int cvtpk(float lo, float hi) {
  unsigned int r;
  asm("v_cvt_pk_bf16_f32 %0, %1, %2" : "=v"(r) : "v"(lo), "v"(hi));
  return r;
}

typedef __attribute__((address_space(3))) short lds_short_t;

// async global->LDS, 16B per lane; LDS dest = wave-uniform base + lane*16
static __device__ __forceinline__ void gload16(const short* g, lds_short_t* l) {
  __builtin_amdgcn_global_load_lds(
      (const __attribute__((address_space(1))) unsigned int*)g,
      (__attribute__((address_space(3))) unsigned int*)l, 16, 0, 0);
}

// merged convert: blocks [0,8192) convert x (2097152 float4);
// blocks [8192,12288) convert the 4 weight matrices (1024 blocks each).
// Same memory ops as the two separate launches — pure launch-overhead cut.
__global__ __launch_bounds__(256) void cvt_all(const float* __restrict__ x,
                                               const float* __restrict__ w0,
                                               const float* __restrict__ w1,
                                               const float* __restrict__ w2,
                                               const float* __restrict__ w3,
                                               short* __restrict__ xb,
                                               short* __restrict__ wc) {
  const int id = blockIdx.x, tid = threadIdx.x;
  if (id < 8192) {
    int i = id * 256 + tid;
    float4 v = ((const float4*)x)[i];
    short4v o;
    o.x = f2bf(v.x); o.y = f2bf(v.y); o.z = f2bf(v.z); o.w = f2bf(v.w);
    ((short4v*)xb)[i] = o;
  } else {
    int wid = id - 8192;
    int y = wid >> 10;
    const float* src = (y == 0) ? w0 : (y == 1) ? w1 : (y == 2) ? w2 : w3;
    int i = (wid & 1023) * 256 + tid;  // < 262144 exactly
    float4 v = ((const float4*)src)[i];
    short4v o;
    o.x = f2bf(v.x); o.y = f2bf(v.y); o.z = f2bf(v.z); o.w = f2bf(v.w);
    ((short4v*)wc)[(size_t)y * 262144 + i] = o;
  }
}

// ---------------------------------------------------------------------------
// 128x128 GEMM, BK=64, single-barrier double-buffer (r11, proven).
// 2-D grid, natural order (r18's XCD swizzle quadrupled FETCH_SIZE).
// MODE 0: QKV fused epilogue -> Qb (prescaled), Kb, Vt.  MODE 1: f32 + bias.
// ---------------------------------------------------------------------------
template <int MODE>
__global__ __launch_bounds__(256) void gemm_db(
    const short* __restrict__ A, const short* __restrict__ W,
    const float* __restrict__ bias, short* __restrict__ Qb,
    short* __restrict__ Kb, short* __restrict__ Vt, float* __restrict__ outF) {
  __shared__ short As[2][128 * 64];
  __shared__ short Bs[2][128 * 64];
  const int tid = threadIdx.x;
  const int m0 = blockIdx.x * 128, n0 = blockIdx.y * 128;
  const int lane = tid & 63, w = tid >> 6;
  const int wr = w >> 1, wc = w & 1;
  const int ll = lane & 15, lh = lane >> 4;

  lds_short_t* As3 = (lds_short_t*)&As[0][0];
  lds_short_t* Bs3 = (lds_short_t*)&Bs[0][0];

  const short* Abase[4];
  const short* Wbase[4];
  int dstOff[4];
#pragma unroll
  for (int i = 0; i < 4; ++i) {
    int slot = i * 256 + tid;
    int row = slot >> 3;
    int gp = (slot & 7) ^ (row & 7);
    Abase[i] = A + (size_t)(m0 + row) * 1024 + gp * 8;
    Wbase[i] = W + (size_t)(n0 + row) * 1024 + gp * 8;
    dstOff[i] = (i * 256 + w * 64) * 8;
  }

  f32x4 acc[4][4] = {};

  // prologue: stage K-tile 0 into buf 0
#pragma unroll
  for (int i = 0; i < 4; ++i) gload16(Abase[i], As3 + dstOff[i]);
#pragma unroll
  for (int i = 0; i < 4; ++i) gload16(Wbase[i], Bs3 + dstOff[i]);
  int cur = 0;

  for (int k0 = 0; k0 < 1024; k0 += 64) {
    __syncthreads();  // buf[cur] staged for all waves; buf^1 free to refill
    if (k0 < 960) {
      int nb = (cur ^ 1) * 8192;
#pragma unroll
      for (int i = 0; i < 4; ++i) gload16(Abase[i] + k0 + 64, As3 + nb + dstOff[i]);
#pragma unroll
      for (int i = 0; i < 4; ++i) gload16(Wbase[i] + k0 + 64, Bs3 + nb + dstOff[i]);
    }

    bf16x8 fa[4][2], fb[4][2];
#pragma unroll
    for (int mi = 0; mi < 4; ++mi) {
      int r = wr * 64 + mi * 16 + ll;
#pragma unroll
      for (int kh = 0; kh < 2; ++kh)
        fa[mi][kh] =
            *(const bf16x8*)&As[cur][r * 64 + (((kh * 4 + lh) ^ (ll & 7)) * 8)];
    }
#pragma unroll
    for (int ni = 0; ni < 4; ++ni) {
      int r = wc * 64 + ni * 16 + ll;
#pragma unroll
      for (int kh = 0; kh < 2; ++kh)
        fb[ni][kh] =
            *(const bf16x8*)&Bs[cur][r * 64 + (((kh * 4 + lh) ^ (ll & 7)) * 8)];
    }
    __builtin_amdgcn_s_setprio(1);
#pragma unroll
    for (int mi = 0; mi < 4; ++mi)
#pragma unroll
      for (int ni = 0; ni < 4; ++ni)
#pragma unroll
        for (int kh = 0; kh < 2; ++kh)
          acc[mi][ni] = __builtin_amdgcn_mfma_f32_16x16x32_bf16(
              fa[mi][kh], fb[ni][kh], acc[mi][ni], 0, 0, 0);
    __builtin_amdgcn_s_setprio(0);
    cur ^= 1;
  }

#pragma unroll
  for (int mi = 0; mi < 4; ++mi) {
#pragma unroll
    for (int ni = 0; ni < 4; ++ni) {
#pragma unroll
      for (int r = 0; r < 4; ++r) {
        int row = m0 + wr * 64 + mi * 16 + lh * 4 + r;
        int n = n0 + wc * 64 + ni * 16 + ll;
        float v = acc[mi][ni][r];
        if constexpr (MODE == 1) {
          outF[(size_t)row * 1024 + n] = v + bias[n];
        } else {
          if (n < 1024) {
            Qb[(size_t)row * 1024 + n] = f2bf(v * 0.18033688f);  // scale*log2e
          } else if (n < 2048) {
            Kb[(size_t)row * 1024 + (n - 1024)] = f2bf(v);
          } else {
            int cc = n - 2048, hh = cc >> 6, dd = cc & 63;
            int bb = row >> 11, ss = row & 2047;
            Vt[(size_t)((bb * 16 + hh) * 64 + dd) * 2048 + ss] = f2bf(v);
          }
        }
      }
    }
  }
}

// Causal flash attention, fixed-max softmax, 32x32 MFMA, swapped QK^T
// (v9: proven 78.3us / absmax 0.0166 — best-known attention).
__global__ __launch_bounds__(256, 4) void attn_v9(const short* __restrict__ Q,
                                                  const short* __restrict__ K,
                                                  const short* __restrict__ Vt,
                                                  short* __restrict__ AO) {
  __shared__ short Ks[2][64 * 64];
  __shared__ short Vs[2][64 * 64];
  const int tid = threadIdx.x, lane = tid & 63, w = tid >> 6;
  const int l31 = lane & 31, lh2 = lane >> 5;
  const int id = blockIdx.x;
  const int bh = id & 63;
  const int qs = id >> 6;
  const int jj = qs >> 2;
  const int qb = (jj == 0) ? qs : (jj == 1) ? 19 - qs : (jj == 2) ? qs - 4 : 23 - qs;
  const int b = bh >> 4, h = bh & 15;
  const int q0 = qb * 128;
  const int R = q0 + w * 32;             // wave's first q-row
  const int kw_last = (R + 31) >> 6;     // wave's diagonal k-tile
  const int kb_max = (q0 + 127) >> 6;    // block's last k-tile
  const short* Qp = Q + (size_t)b * Sc * Dc + h * 64;
  const short* Kp = K + (size_t)b * Sc * Dc + h * 64;
  const short* Vp = Vt + (size_t)bh * 64 * Sc;

  lds_short_t* Ks3 = (lds_short_t*)Ks;
  lds_short_t* Vs3 = (lds_short_t*)Vs;

  bf16x8 qf[4];
#pragma unroll
  for (int dk = 0; dk < 4; ++dk)
    qf[dk] = *(const bf16x8*)&Qp[(size_t)(R + l31) * Dc + dk * 16 + lh2 * 8];

  const short* Kst[2];
  const short* Vst[2];
  int ldsOff[2];
#pragma unroll
  for (int i = 0; i < 2; ++i) {
    int slot = i * 256 + w * 64 + lane;
    int row = slot >> 3;
    int col = ((slot & 7) ^ (row & 7)) * 8;  // pre-swizzled source group
    Kst[i] = Kp + (size_t)row * 1024 + col;
    Vst[i] = Vp + (size_t)row * 2048 + col;
    ldsOff[i] = (i * 256 + w * 64) * 8;
  }

  f32x16 o0 = {}, o1 = {};
  float lrun = 0.f;

#pragma unroll
  for (int i = 0; i < 2; ++i) {
    gload16(Kst[i], Ks3 + ldsOff[i]);
    gload16(Vst[i], Vs3 + ldsOff[i]);
  }
  int cur = 0;

  for (int kb = 0; kb <= kb_max; ++kb) {
    __syncthreads();
    if (kb < kb_max) {
      int nb = cur ^ 1;
#pragma unroll
      for (int i = 0; i < 2; ++i) {
        gload16(Kst[i] + (size_t)(kb + 1) * 65536, Ks3 + nb * 4096 + ldsOff[i]);
        gload16(Vst[i] + (kb + 1) * 64, Vs3 + nb * 4096 + ldsOff[i]);
      }
    }

    if (kb <= kw_last) {
      const bool diag = (kb == kw_last);
      const bool skipHi = diag && ((R & 63) == 0);

      f32x16 sv0 = {}, sv1 = {};
      {
        const int row = l31, rx = row & 7;
#pragma unroll
        for (int dk = 0; dk < 4; ++dk) {
          bf16x8 kf =
              *(const bf16x8*)&Ks[cur][row * 64 + (((dk * 2 + lh2) ^ rx) * 8)];
          sv0 = __builtin_amdgcn_mfma_f32_32x32x16_bf16(kf, qf[dk], sv0, 0, 0, 0);
        }
      }
      if (!skipHi) {
        const int row = 32 + l31, rx = row & 7;
#pragma unroll
        for (int dk = 0; dk < 4; ++dk) {
          bf16x8 kf =
              *(const bf16x8*)&Ks[cur][row * 64 + (((dk * 2 + lh2) ^ rx) * 8)];
          sv1 = __builtin_amdgcn_mfma_f32_32x32x16_bf16(kf, qf[dk], sv1, 0, 0, 0);
        }
      }

      float ts = 0.f;
      if (!diag) {
#pragma unroll
        for (int r = 0; r < 16; ++r) {
          float e0 = exp2f(sv0[r]);
          float e1 = exp2f(sv1[r]);
          sv0[r] = e0; sv1[r] = e1;
          ts += e0 + e1;
        }
      } else if (skipHi) {
#pragma unroll
        for (int r = 0; r < 16; ++r) {
          int kl = (r & 3) + 8 * (r >> 2) + 4 * lh2;
          float e = (kl > l31) ? 0.f : exp2f(sv0[r]);
          sv0[r] = e;
          ts += e;
        }
      } else {
#pragma unroll
        for (int r = 0; r < 16; ++r) {
          float e = exp2f(sv0[r]);
          sv0[r] = e;
          ts += e;
        }
#pragma unroll
        for (int r = 0; r < 16; ++r) {
          int kl = (r & 3) + 8 * (r >> 2) + 4 * lh2;
          float e = (kl > l31) ? 0.f : exp2f(sv1[r]);
          sv1[r] = e;
          ts += e;
        }
      }
      lrun += ts;

      short4v pa[8];
#pragma unroll
      for (int t = 0; t < 4; ++t) {
        union { unsigned int u[2]; short4v s; } pk;
        pk.u[0] = cvtpk(sv0[4 * t + 0], sv0[4 * t + 1]);
        pk.u[1] = cvtpk(sv0[4 * t + 2], sv0[4 * t + 3]);
        pa[t] = pk.s;
      }
      if (skipHi) {
        const int r0 = l31, rx0 = r0 & 7;
        const int r1 = 32 + l31, rx1 = r1 & 7;
#pragma unroll
        for (int t = 0; t < 4; ++t) {
          short4v vb0 =
              *(const short4v*)&Vs[cur][r0 * 64 + ((t ^ rx0) * 8) + lh2 * 4];
          o0 = __builtin_amdgcn_mfma_f32_32x32x8bf16_1k(pa[t], vb0, o0, 0, 0, 0);
          short4v vb1 =
              *(const short4v*)&Vs[cur][r1 * 64 + ((t ^ rx1) * 8) + lh2 * 4];
          o1 = __builtin_amdgcn_mfma_f32_32x32x8bf16_1k(pa[t], vb1, o1, 0, 0, 0);
        }
      } else {
#pragma unroll
        for (int t = 0; t < 4; ++t) {
          union { unsigned int u[2]; short4v s; } pk;
          pk.u[0] = cvtpk(sv1[4 * t + 0], sv1[4 * t + 1]);
          pk.u[1] = cvtpk(sv1[4 * t + 2], sv1[4 * t + 3]);
          pa[4 + t] = pk.s;
        }
        const int r0 = l31, rx0 = r0 & 7;
        const int r1 = 32 + l31, rx1 = r1 & 7;
#pragma unroll
        for (int t = 0; t < 8; ++t) {
          short4v vb0 =
              *(const short4v*)&Vs[cur][r0 * 64 + ((t ^ rx0) * 8) + lh2 * 4];
          o0 = __builtin_amdgcn_mfma_f32_32x32x8bf16_1k(pa[t], vb0, o0, 0, 0, 0);
        }
#pragma unroll
        for (int t = 0; t < 8; ++t) {
          short4v vb1 =
              *(const short4v*)&Vs[cur][r1 * 64 + ((t ^ rx1) * 8) + lh2 * 4];
          o1 = __builtin_amdgcn_mfma_f32_32x32x8bf16_1k(pa[t], vb1, o1, 0, 0, 0);
        }
      }
    }
    cur ^= 1;
  }

  float ltot = lrun + __shfl_xor(lrun, 32);
#pragma unroll
  for (int r = 0; r < 16; ++r) {
    int qr = (r & 3) + 8 * (r >> 2) + 4 * lh2;
    float lq = __shfl(ltot, qr);
    float inv = 1.0f / lq;
    int rowg = R + qr;
    AO[((size_t)(b * Sc + rowg)) * Dc + h * 64 + l31] = f2bf(o0[r] * inv);
    AO[((size_t)(b * Sc + rowg)) * Dc + h * 64 + 32 + l31] = f2bf(o1[r] * inv);
  }
}

extern "C" void kernel_launch(void* const* d_in, const int* in_sizes, int n_in,
                              void* d_out, int out_size, void* d_ws,
                              size_t ws_size, hipStream_t stream) {
  const float* x = (const float*)d_in[0];
  const float* Wq = (const float*)d_in[1];
  const float* Wk = (const float*)d_in[2];
  const float* Wv = (const float*)d_in[3];
  const float* Wo = (const float*)d_in[4];
  const float* bo = (const float*)d_in[5];
  float* out = (float*)d_out;

  short* Qb = (short*)d_out;
  short* Kb = Qb + (size_t)8192 * 1024;
  short* xb = (short*)d_ws;
  short* AOb = xb;  // xb dead after QKV GEMM; attention writes AOb
  short* Wc = xb + (size_t)8192 * 1024;
  short* Vt = Wc + (size_t)4096 * 1024;

  dim3 blk(256);
  hipLaunchKernelGGL(cvt_all, dim3(12288), blk, 0, stream, x, Wq, Wk, Wv, Wo,
                     xb, Wc);

  hipLaunchKernelGGL((gemm_db<0>), dim3(64, 24), blk, 0, stream, xb, Wc,
                     (const float*)nullptr, Qb, Kb, Vt, (float*)nullptr);

  hipLaunchKernelGGL(attn_v9, dim3(1024), blk, 0, stream, Qb, Kb, Vt, AOb);

  hipLaunchKernelGGL((gemm_db<1>), dim3(64, 8), blk, 0, stream, AOb,
                     Wc + (size_t)3072 * 1024, bo, (short*)nullptr,
                     (short*)nullptr, (short*)nullptr, out);
}